// Round 9
// baseline (510.889 us; speedup 1.0000x reference)
//
#include <hip/hip_runtime.h>
#include <hip/hip_bf16.h>

// Problem constants (B=4, L=2048, D=512, M=1200, H=6)
// KEY INSIGHT: keyval is broadcast over L -> K rows identical -> softmax == 1/L exactly,
// mha == V[b] (per-batch constant), and leaky(slope=1) is identity so W2a@W2b folds.
// R9 = R8 minus all split-K atomics and the memset dispatch:
//  - kv writes direct into 8 per-kc V slabs (oc sums slabs inline)
//  - fold GEMM writes 4 separate Wf slabs (plain stores); k4 tcast sums slabs
//  - only oc (2KB) needs zeroing, done by one k1 block
// 5 launches total; every stage's sm-fill share distributed over its whole grid.

typedef __bf16 bf16x8 __attribute__((ext_vector_type(8)));
typedef float f32x4 __attribute__((ext_vector_type(4)));

constexpr size_t OUT3_N = 4ull * 2048 * 512;            // 4,194,304
constexpr size_t SM_N4  = (4ull * 6 * 2048 * 2048) / 4; // 25,165,824 f32x4
constexpr float  SMV    = 1.0f / 2048.0f;

// fill slice schedule (f32x4 units) — disjoint, covers SM exactly
constexpr size_t S1 = 0,        C1 = 5375000;
constexpr size_t S3 = 5375000,  C3 = 5687500;
constexpr size_t S4 = 11062500, C4 = 4750000;
constexpr size_t S5 = 15812500, C5 = 5187500;
constexpr size_t S6 = 21000000, C6 = 4165824;
static_assert(S6 + C6 == SM_N4, "fill slices must cover sm");

__device__ __forceinline__ void fill_slice(f32x4* __restrict__ p, size_t base, size_t cnt,
                                           int fb, int nfb){
    const f32x4 v = { SMV, SMV, SMV, SMV };
    const size_t stride = (size_t)nfb * 256;
    for (size_t j = (size_t)fb * 256 + threadIdx.x; j < cnt; j += stride)
        __builtin_nontemporal_store(v, p + base + j);
}

// ---------------- bf16 MFMA GEMM tile: C[64x64 at bm,bn] = A[M,K] @ BT[N,K]^T over [k0beg,k0end)
// BK=64, 4 waves 2x2, global_load_lds width16, XOR-swizzled LDS (16B chunks: c8' = c8 ^ (r&7))
// OutT: float = plain fp32 store, __bf16 = bf16 store
template<typename OutT>
__device__ void gemm_tile(const __bf16* __restrict__ A, const __bf16* __restrict__ BT,
                          OutT* __restrict__ C, int Ndim, int Kdim,
                          int bm, int bn, int k0beg, int k0end){
    __shared__ __bf16 As[64 * 64];
    __shared__ __bf16 Bs[64 * 64];
    const int tid = threadIdx.x, wave = tid >> 6, lane = tid & 63;
    const int r_st = wave * 8 + (lane >> 3);
    const int c8g  = (lane & 7) ^ (r_st & 7);
    const __bf16* Ag = A  + (size_t)(bm + r_st) * Kdim + c8g * 8;
    const __bf16* Bg = BT + (size_t)(bn + r_st) * Kdim + c8g * 8;
    const size_t rowskip = (size_t)32 * Kdim;
    const int wm = (wave >> 1) * 32, wn = (wave & 1) * 32;
    const int lm = lane & 15, lq = lane >> 4;
    f32x4 acc[2][2] = {};
    for (int k0 = k0beg; k0 < k0end; k0 += 64){
        __builtin_amdgcn_global_load_lds(
            (const __attribute__((address_space(1))) void*)(Ag + k0),
            (__attribute__((address_space(3))) void*)&As[wave * 512], 16, 0, 0);
        __builtin_amdgcn_global_load_lds(
            (const __attribute__((address_space(1))) void*)(Ag + k0 + rowskip),
            (__attribute__((address_space(3))) void*)&As[2048 + wave * 512], 16, 0, 0);
        __builtin_amdgcn_global_load_lds(
            (const __attribute__((address_space(1))) void*)(Bg + k0),
            (__attribute__((address_space(3))) void*)&Bs[wave * 512], 16, 0, 0);
        __builtin_amdgcn_global_load_lds(
            (const __attribute__((address_space(1))) void*)(Bg + k0 + rowskip),
            (__attribute__((address_space(3))) void*)&Bs[2048 + wave * 512], 16, 0, 0);
        __syncthreads();
        #pragma unroll
        for (int kb = 0; kb < 64; kb += 32){
            const int sw = (((kb >> 3) + lq) ^ (lm & 7)) << 3;
            bf16x8 a0 = *(const bf16x8*)&As[(wm + lm) * 64 + sw];
            bf16x8 a1 = *(const bf16x8*)&As[(wm + 16 + lm) * 64 + sw];
            bf16x8 b0 = *(const bf16x8*)&Bs[(wn + lm) * 64 + sw];
            bf16x8 b1 = *(const bf16x8*)&Bs[(wn + 16 + lm) * 64 + sw];
            acc[0][0] = __builtin_amdgcn_mfma_f32_16x16x32_bf16(a0, b0, acc[0][0], 0, 0, 0);
            acc[0][1] = __builtin_amdgcn_mfma_f32_16x16x32_bf16(a0, b1, acc[0][1], 0, 0, 0);
            acc[1][0] = __builtin_amdgcn_mfma_f32_16x16x32_bf16(a1, b0, acc[1][0], 0, 0, 0);
            acc[1][1] = __builtin_amdgcn_mfma_f32_16x16x32_bf16(a1, b1, acc[1][1], 0, 0, 0);
        }
        __syncthreads();
    }
    #pragma unroll
    for (int mi = 0; mi < 2; ++mi)
      #pragma unroll
      for (int ni = 0; ni < 2; ++ni)
        #pragma unroll
        for (int r = 0; r < 4; ++r){
            int row = bm + wm + mi * 16 + lq * 4 + r;   // C/D: row=(lane>>4)*4+reg
            int col = bn + wn + ni * 16 + lm;           //      col=lane&15
            C[(size_t)row * Ndim + col] = (OutT)acc[mi][ni][r];
        }
}

// ---------------- k1: prep + kv split-K (direct slab writes) + oc zero; all blocks fill C1
__global__ __launch_bounds__(256) void k1_prep_kv(const float* __restrict__ W2a,
        const float* __restrict__ b2a, __bf16* __restrict__ A1,
        const float* __restrict__ W2b, __bf16* __restrict__ W2bT,
        const float* __restrict__ keyval, const float* __restrict__ Wkv,
        const float* __restrict__ bkv, float* __restrict__ Vs,  // [8][4][1200]
        float* __restrict__ oc, f32x4* __restrict__ smf){
    __shared__ float sh[32 * 33];
    const int bid = blockIdx.x, tid = threadIdx.x;
    if (bid < 1152){
        int r = bid >> 1;
        int c = (bid & 1) * 1024 + tid * 4;
        float4 v;
        if (r < 512)       v = *(const float4*)(W2a + (size_t)r * 2048 + c);
        else if (r == 512) v = *(const float4*)(b2a + c);
        else               v = make_float4(0.f, 0.f, 0.f, 0.f);
        __bf16* o = A1 + (size_t)r * 2048 + c;
        o[0] = (__bf16)v.x; o[1] = (__bf16)v.y; o[2] = (__bf16)v.z; o[3] = (__bf16)v.w;
    } else if (bid < 2176){
        int t = bid - 1152;                    // 1024 tiles over W2b [2048][512]
        int c0 = (t & 15) * 32, r0 = (t >> 4) * 32;
        int tx = tid & 31, ty = tid >> 5;
        for (int i = ty; i < 32; i += 8)
            sh[i * 33 + tx] = W2b[(size_t)(r0 + i) * 512 + c0 + tx];
        __syncthreads();
        for (int i = ty; i < 32; i += 8)
            W2bT[(size_t)(c0 + i) * 2048 + r0 + tx] = (__bf16)sh[tx * 33 + i];
    } else if (bid < 2336){
        int i = bid - 2176;                    // 160: b(4) x mc(5) x kc(8)
        int b = i & 3, mc = (i >> 2) % 5, kc = i / 20;
        int m = mc * 256 + tid;
        if (m < 1200){
            float acc = (kc == 0) ? bkv[1200 + m] : 0.f;
            const float* kvb = keyval + (size_t)b * 512;
            int d0 = kc * 64;
            #pragma unroll 8
            for (int d = d0; d < d0 + 64; ++d)
                acc += kvb[d] * Wkv[(size_t)d * 2400 + 1200 + m];
            Vs[kc * 4800 + b * 1200 + m] = acc;   // direct write, no atomics/zeroing
        }
    } else if (bid == 2336){
        ((f32x4*)oc)[tid]       = (f32x4){0.f, 0.f, 0.f, 0.f};   // zero oc (2048 floats)
        ((f32x4*)oc)[tid + 256] = (f32x4){0.f, 0.f, 0.f, 0.f};
    }
    fill_slice(smf, S1, C1, bid, 2848);
}

// ---------------- k3: fold GEMM -> 4 Wf slabs (plain stores) + oc GEMV (sums V slabs); fill C3
__global__ __launch_bounds__(256) void k3_fold_oc(const __bf16* __restrict__ A1,
        const __bf16* __restrict__ W2bT, float* __restrict__ Wf,   // [4][576][512]
        const float* __restrict__ Vs, const float* __restrict__ Wff,
        const float* __restrict__ bff, float* __restrict__ oc, f32x4* __restrict__ smf){
    const int bid = blockIdx.x, tid = threadIdx.x;
    if (bid < 288){                            // tile(9x8) x kc(4) over [576x512], K=2048
        int tile = bid % 72, kc = bid / 72;
        gemm_tile<float>(A1, W2bT, Wf + (size_t)kc * 294912, 512, 2048,
                         (tile % 9) * 64, (tile / 9) * 64, kc * 512, (kc + 1) * 512);
    } else if (bid < 384){                     // oc: b(4) x jc(2) x kc(12), K=1200
        int i = bid - 288;
        int b = i & 3, jc = (i >> 2) & 1, kc = i >> 3;
        int j = jc * 256 + tid;
        float acc = (kc == 0) ? bff[j] : 0.f;
        int m0 = kc * 100;
        for (int m = m0; m < m0 + 100; ++m){
            float vs = 0.f;
            #pragma unroll
            for (int s = 0; s < 8; ++s) vs += Vs[s * 4800 + b * 1200 + m];
            acc += vs * Wff[(size_t)m * 512 + j];
        }
        atomicAdd(&oc[b * 512 + j], acc);      // 12-way tiny atomics only
    }
    fill_slice(smf, S3, C3, bid, 2048);
}

// ---------------- k4: ln1 + tcast (sum 4 Wf slabs -> WfT) + bfsum; fill C4
__global__ __launch_bounds__(256) void k4_ln1_tcast(const float* __restrict__ q,
        const float* __restrict__ oc, const float* __restrict__ g1,
        const float* __restrict__ b1, __bf16* __restrict__ Xb,
        const float* __restrict__ Wf, __bf16* __restrict__ WfT,
        float* __restrict__ bf, f32x4* __restrict__ smf){
    __shared__ float sh[32 * 33];
    const int bid = blockIdx.x, t = threadIdx.x;
    if (bid < 8192){
        const int b = bid >> 11;
        const size_t base = (size_t)bid * 512;
        float2 qv = *(const float2*)(q + base + 2 * t);
        float2 ov = *(const float2*)(oc + (size_t)b * 512 + 2 * t);
        float v0 = qv.x + ov.x, v1 = qv.y + ov.y;
        float s = v0 + v1, ss = v0 * v0 + v1 * v1;
        for (int off = 32; off; off >>= 1){ s += __shfl_down(s, off); ss += __shfl_down(ss, off); }
        int wv = t >> 6, ln = t & 63;
        if (ln == 0){ sh[wv] = s; sh[4 + wv] = ss; }
        __syncthreads();
        if (t == 0){
            float S  = sh[0] + sh[1] + sh[2] + sh[3];
            float SS = sh[4] + sh[5] + sh[6] + sh[7];
            float m = S * (1.0f / 512.0f);
            float var = SS * (1.0f / 512.0f) - m * m;
            sh[0] = m; sh[1] = rsqrtf(var + 1e-5f);
        }
        __syncthreads();
        float m = sh[0], r = sh[1];
        float2 gv = *(const float2*)(g1 + 2 * t);
        float2 bv = *(const float2*)(b1 + 2 * t);
        union { __bf16 h[2]; unsigned u; } pk;
        pk.h[0] = (__bf16)((v0 - m) * r * gv.x + bv.x);
        pk.h[1] = (__bf16)((v1 - m) * r * gv.y + bv.y);
        *(unsigned*)(Xb + base + 2 * t) = pk.u;
    } else if (bid < 8448){
        int tt = bid - 8192;                   // 256 tiles over Wf [512][512], sum 4 slabs
        int c0 = (tt & 15) * 32, r0 = (tt >> 4) * 32;
        int tx = t & 31, ty = t >> 5;
        for (int i = ty; i < 32; i += 8){
            size_t off = (size_t)(r0 + i) * 512 + c0 + tx;
            sh[i * 33 + tx] = Wf[off] + Wf[294912 + off] + Wf[589824 + off] + Wf[884736 + off];
        }
        __syncthreads();
        for (int i = ty; i < 32; i += 8)
            WfT[(size_t)(c0 + i) * 512 + r0 + tx] = (__bf16)sh[tx * 33 + i];
    } else if (bid < 8450){
        int j = (bid - 8448) * 256 + t;        // bfsum = sum of 4 slab rows 512
        bf[j] = Wf[262144 + j] + Wf[294912 + 262144 + j]
              + Wf[589824 + 262144 + j] + Wf[884736 + 262144 + j];
    }
    fill_slice(smf, S4, C4, bid, 8960);
}

// ---------------- k5: main GEMM (out2 = X @ Wfold, bf16 out); fill C5
__global__ __launch_bounds__(256) void k5_gemm(const __bf16* __restrict__ X,
        const __bf16* __restrict__ WfT, __bf16* __restrict__ out2, f32x4* __restrict__ smf){
    const int bid = blockIdx.x;
    if (bid < 1024){                           // 128 x 8 tiles
        gemm_tile<__bf16>(X, WfT, out2, 512, 512, (bid >> 3) * 64, (bid & 7) * 64, 0, 512);
    }
    fill_slice(smf, S5, C5, bid, 2048);
}

// ---------------- k6: ln2; fill C6
__global__ __launch_bounds__(256) void k6_ln2(const __bf16* __restrict__ X,
        const __bf16* __restrict__ o2, const float* __restrict__ bfrow,
        const float* __restrict__ b2b, const float* __restrict__ g2,
        const float* __restrict__ b2, const float* __restrict__ keyval,
        float* __restrict__ out3, f32x4* __restrict__ smf){
    __shared__ float sh[8];
    const int bid = blockIdx.x, t = threadIdx.x;
    if (bid < 8192){
        const int b = bid >> 11;
        const size_t base = (size_t)bid * 512;
        union { unsigned u; __bf16 h[2]; } xv, yv;
        xv.u = *(const unsigned*)(X + base + 2 * t);
        yv.u = *(const unsigned*)(o2 + base + 2 * t);
        float f0 = bfrow[2 * t] + b2b[2 * t], f1 = bfrow[2 * t + 1] + b2b[2 * t + 1];
        float v0 = (float)xv.h[0] + (float)yv.h[0] + f0;
        float v1 = (float)xv.h[1] + (float)yv.h[1] + f1;
        float s = v0 + v1, ss = v0 * v0 + v1 * v1;
        for (int off = 32; off; off >>= 1){ s += __shfl_down(s, off); ss += __shfl_down(ss, off); }
        int wv = t >> 6, ln = t & 63;
        if (ln == 0){ sh[wv] = s; sh[4 + wv] = ss; }
        __syncthreads();
        if (t == 0){
            float S  = sh[0] + sh[1] + sh[2] + sh[3];
            float SS = sh[4] + sh[5] + sh[6] + sh[7];
            float m = S * (1.0f / 512.0f);
            float var = SS * (1.0f / 512.0f) - m * m;
            sh[0] = m; sh[1] = rsqrtf(var + 1e-5f);
        }
        __syncthreads();
        float m = sh[0], r = sh[1];
        float2 gv = *(const float2*)(g2 + 2 * t);
        float2 bv = *(const float2*)(b2 + 2 * t);
        float2 kv = *(const float2*)(keyval + (size_t)b * 512 + 2 * t);
        float y0 = (v0 - m) * r * gv.x + bv.x + kv.x;
        float y1 = (v1 - m) * r * gv.y + bv.y + kv.y;
        *(float2*)(out3 + base + 2 * t) = make_float2(y0, y1);
    }
    fill_slice(smf, S6, C6, bid, 8704);
}

// ---------------- launch ----------------
extern "C" void kernel_launch(void* const* d_in, const int* in_sizes, int n_in,
                              void* d_out, int out_size, void* d_ws, size_t ws_size,
                              hipStream_t stream){
    const float* query  = (const float*)d_in[0];
    const float* keyval = (const float*)d_in[1];
    // d_in[2] Wq, d_in[3] bq: provably unused (softmax is uniform regardless of Q)
    const float* Wkv = (const float*)d_in[4];
    const float* bkv = (const float*)d_in[5];
    const float* Wff = (const float*)d_in[6];
    const float* bff = (const float*)d_in[7];
    const float* g1  = (const float*)d_in[8];
    const float* b1  = (const float*)d_in[9];
    const float* W2a = (const float*)d_in[10];
    const float* b2a = (const float*)d_in[11];
    const float* W2b = (const float*)d_in[12];
    const float* b2b = (const float*)d_in[13];
    const float* g2  = (const float*)d_in[14];
    const float* b2  = (const float*)d_in[15];

    float* out3 = (float*)d_out;
    f32x4* smf  = (f32x4*)(out3 + OUT3_N);

    // scratch (~28 MB): prefer d_ws; fall back to the sm region (filled last)
    char* base = (ws_size >= (64ull << 20)) ? (char*)d_ws : (char*)smf;
    float*  t_Wf   = (float*)base;                      // [4][576][512] fp32 slabs
    float*  t_oc   = t_Wf + 1179648;                    // [4][512]
    float*  t_Vs   = t_oc + 2048;                       // [8][4][1200]
    float*  t_bf   = t_Vs + 38400;                      // [512] summed bfold row
    __bf16* t_A1   = (__bf16*)(t_bf + 512);             // [576][2048]
    __bf16* t_W2bT = t_A1 + 1179648;                    // [512][2048]
    __bf16* t_WfT  = t_W2bT + 1048576;                  // [512][512]
    __bf16* t_X    = t_WfT + 262144;                    // [8192][512]
    __bf16* t_out2 = t_X + 4194304;                     // [8192][512] bf16

    k1_prep_kv<<<2848, 256, 0, stream>>>(W2a, b2a, t_A1, W2b, t_W2bT,
                                         keyval, Wkv, bkv, t_Vs, t_oc, smf);
    k3_fold_oc<<<2048, 256, 0, stream>>>(t_A1, t_W2bT, t_Wf, t_Vs, Wff, bff, t_oc, smf);
    k4_ln1_tcast<<<8960, 256, 0, stream>>>(query, t_oc, g1, b1, t_X, t_Wf, t_WfT, t_bf, smf);
    k5_gemm<<<2048, 256, 0, stream>>>(t_X, t_WfT, t_out2, smf);
    k6_ln2<<<8704, 256, 0, stream>>>(t_X, t_out2, t_bf, b2b, g2, b2, keyval, out3, smf);
}

// Round 10
// 489.402 us; speedup vs baseline: 1.0439x; 1.0439x over previous
//
#include <hip/hip_runtime.h>
#include <hip/hip_bf16.h>

// Problem constants (B=4, L=2048, D=512, M=1200, H=6)
// KEY INSIGHT: keyval is broadcast over L -> K rows identical -> softmax == 1/L exactly,
// mha == V[b] (per-batch constant), and leaky(slope=1) is identity so W2a@W2b folds.
// R10 = R8 (best measured: 488.5 µs). R9's slab de-atomization added 4x Wf + 8x Vs traffic
// and regressed; reverted. Chain: memset + 5 fused stages; every stage's sm-fill share
// distributed across its whole grid with nontemporal stores.

typedef __bf16 bf16x8 __attribute__((ext_vector_type(8)));
typedef float f32x4 __attribute__((ext_vector_type(4)));

constexpr size_t OUT3_N = 4ull * 2048 * 512;            // 4,194,304
constexpr size_t SM_N4  = (4ull * 6 * 2048 * 2048) / 4; // 25,165,824 f32x4
constexpr float  SMV    = 1.0f / 2048.0f;

// fill slice schedule (f32x4 units) — disjoint, covers SM exactly
constexpr size_t S1 = 0,        C1 = 5375000;
constexpr size_t S3 = 5375000,  C3 = 5687500;
constexpr size_t S4 = 11062500, C4 = 4750000;
constexpr size_t S5 = 15812500, C5 = 5187500;
constexpr size_t S6 = 21000000, C6 = 4165824;
static_assert(S6 + C6 == SM_N4, "fill slices must cover sm");

__device__ __forceinline__ void fill_slice(f32x4* __restrict__ p, size_t base, size_t cnt,
                                           int fb, int nfb){
    const f32x4 v = { SMV, SMV, SMV, SMV };
    const size_t stride = (size_t)nfb * 256;
    for (size_t j = (size_t)fb * 256 + threadIdx.x; j < cnt; j += stride)
        __builtin_nontemporal_store(v, p + base + j);
}

// ---------------- bf16 MFMA GEMM tile: C[64x64 at bm,bn] (+)= A[M,K] @ BT[N,K]^T over [k0beg,k0end)
// BK=64, 4 waves 2x2, global_load_lds width16, XOR-swizzled LDS (16B chunks: c8' = c8 ^ (r&7))
// MODE: 1 = atomicAdd fp32 (split-K), 2 = store bf16
template<int MODE, typename OutT>
__device__ void gemm_tile(const __bf16* __restrict__ A, const __bf16* __restrict__ BT,
                          OutT* __restrict__ C, int Ndim, int Kdim,
                          int bm, int bn, int k0beg, int k0end){
    __shared__ __bf16 As[64 * 64];
    __shared__ __bf16 Bs[64 * 64];
    const int tid = threadIdx.x, wave = tid >> 6, lane = tid & 63;
    const int r_st = wave * 8 + (lane >> 3);
    const int c8g  = (lane & 7) ^ (r_st & 7);
    const __bf16* Ag = A  + (size_t)(bm + r_st) * Kdim + c8g * 8;
    const __bf16* Bg = BT + (size_t)(bn + r_st) * Kdim + c8g * 8;
    const size_t rowskip = (size_t)32 * Kdim;
    const int wm = (wave >> 1) * 32, wn = (wave & 1) * 32;
    const int lm = lane & 15, lq = lane >> 4;
    f32x4 acc[2][2] = {};
    for (int k0 = k0beg; k0 < k0end; k0 += 64){
        __builtin_amdgcn_global_load_lds(
            (const __attribute__((address_space(1))) void*)(Ag + k0),
            (__attribute__((address_space(3))) void*)&As[wave * 512], 16, 0, 0);
        __builtin_amdgcn_global_load_lds(
            (const __attribute__((address_space(1))) void*)(Ag + k0 + rowskip),
            (__attribute__((address_space(3))) void*)&As[2048 + wave * 512], 16, 0, 0);
        __builtin_amdgcn_global_load_lds(
            (const __attribute__((address_space(1))) void*)(Bg + k0),
            (__attribute__((address_space(3))) void*)&Bs[wave * 512], 16, 0, 0);
        __builtin_amdgcn_global_load_lds(
            (const __attribute__((address_space(1))) void*)(Bg + k0 + rowskip),
            (__attribute__((address_space(3))) void*)&Bs[2048 + wave * 512], 16, 0, 0);
        __syncthreads();
        #pragma unroll
        for (int kb = 0; kb < 64; kb += 32){
            const int sw = (((kb >> 3) + lq) ^ (lm & 7)) << 3;
            bf16x8 a0 = *(const bf16x8*)&As[(wm + lm) * 64 + sw];
            bf16x8 a1 = *(const bf16x8*)&As[(wm + 16 + lm) * 64 + sw];
            bf16x8 b0 = *(const bf16x8*)&Bs[(wn + lm) * 64 + sw];
            bf16x8 b1 = *(const bf16x8*)&Bs[(wn + 16 + lm) * 64 + sw];
            acc[0][0] = __builtin_amdgcn_mfma_f32_16x16x32_bf16(a0, b0, acc[0][0], 0, 0, 0);
            acc[0][1] = __builtin_amdgcn_mfma_f32_16x16x32_bf16(a0, b1, acc[0][1], 0, 0, 0);
            acc[1][0] = __builtin_amdgcn_mfma_f32_16x16x32_bf16(a1, b0, acc[1][0], 0, 0, 0);
            acc[1][1] = __builtin_amdgcn_mfma_f32_16x16x32_bf16(a1, b1, acc[1][1], 0, 0, 0);
        }
        __syncthreads();
    }
    #pragma unroll
    for (int mi = 0; mi < 2; ++mi)
      #pragma unroll
      for (int ni = 0; ni < 2; ++ni)
        #pragma unroll
        for (int r = 0; r < 4; ++r){
            int row = bm + wm + mi * 16 + lq * 4 + r;   // C/D: row=(lane>>4)*4+reg
            int col = bn + wn + ni * 16 + lm;           //      col=lane&15
            if (MODE == 1) atomicAdd((float*)&C[(size_t)row * Ndim + col], acc[mi][ni][r]);
            else           C[(size_t)row * Ndim + col] = (OutT)acc[mi][ni][r];
        }
}

// ---------------- k1: prep + kv split-K; ALL blocks then fill their C1 share ----------------
__global__ __launch_bounds__(256) void k1_prep_kv(const float* __restrict__ W2a,
        const float* __restrict__ b2a, __bf16* __restrict__ A1,
        const float* __restrict__ W2b, __bf16* __restrict__ W2bT,
        const float* __restrict__ keyval, const float* __restrict__ Wkv,
        const float* __restrict__ bkv, float* __restrict__ V, f32x4* __restrict__ smf){
    __shared__ float sh[32 * 33];
    const int bid = blockIdx.x, tid = threadIdx.x;
    if (bid < 1152){
        int r = bid >> 1;
        int c = (bid & 1) * 1024 + tid * 4;
        float4 v;
        if (r < 512)       v = *(const float4*)(W2a + (size_t)r * 2048 + c);
        else if (r == 512) v = *(const float4*)(b2a + c);
        else               v = make_float4(0.f, 0.f, 0.f, 0.f);
        __bf16* o = A1 + (size_t)r * 2048 + c;
        o[0] = (__bf16)v.x; o[1] = (__bf16)v.y; o[2] = (__bf16)v.z; o[3] = (__bf16)v.w;
    } else if (bid < 2176){
        int t = bid - 1152;                    // 1024 tiles over W2b [2048][512]
        int c0 = (t & 15) * 32, r0 = (t >> 4) * 32;
        int tx = tid & 31, ty = tid >> 5;
        for (int i = ty; i < 32; i += 8)
            sh[i * 33 + tx] = W2b[(size_t)(r0 + i) * 512 + c0 + tx];
        __syncthreads();
        for (int i = ty; i < 32; i += 8)
            W2bT[(size_t)(c0 + i) * 2048 + r0 + tx] = (__bf16)sh[tx * 33 + i];
    } else if (bid < 2336){
        int i = bid - 2176;                    // 160: b(4) x mc(5) x kc(8)
        int b = i & 3, mc = (i >> 2) % 5, kc = i / 20;
        int m = mc * 256 + tid;
        if (m < 1200){
            float acc = (kc == 0) ? bkv[1200 + m] : 0.f;
            const float* kvb = keyval + (size_t)b * 512;
            int d0 = kc * 64;
            #pragma unroll 8
            for (int d = d0; d < d0 + 64; ++d)
                acc += kvb[d] * Wkv[(size_t)d * 2400 + 1200 + m];
            atomicAdd(&V[b * 1200 + m], acc);
        }
    }
    fill_slice(smf, S1, C1, bid, 2848);
}

// ---------------- k3: fold GEMM split-K + oc GEMV; ALL blocks fill C3 share ----------------
__global__ __launch_bounds__(256) void k3_fold_oc(const __bf16* __restrict__ A1,
        const __bf16* __restrict__ W2bT, float* __restrict__ Wf,
        const float* __restrict__ V, const float* __restrict__ Wff,
        const float* __restrict__ bff, float* __restrict__ oc, f32x4* __restrict__ smf){
    const int bid = blockIdx.x, tid = threadIdx.x;
    if (bid < 288){                            // tile(9x8) x kc(4) over [576x512], K=2048
        int tile = bid % 72, kc = bid / 72;
        gemm_tile<1>(A1, W2bT, Wf, 512, 2048, (tile % 9) * 64, (tile / 9) * 64,
                     kc * 512, (kc + 1) * 512);
    } else if (bid < 384){                     // oc: b(4) x jc(2) x kc(12), K=1200
        int i = bid - 288;
        int b = i & 3, jc = (i >> 2) & 1, kc = i >> 3;
        int j = jc * 256 + tid;
        float acc = (kc == 0) ? bff[j] : 0.f;
        const float* vb = V + b * 1200;
        int m0 = kc * 100;
        #pragma unroll 5
        for (int m = m0; m < m0 + 100; ++m)
            acc += vb[m] * Wff[(size_t)m * 512 + j];
        atomicAdd(&oc[b * 512 + j], acc);
    }
    fill_slice(smf, S3, C3, bid, 2048);
}

// ---------------- k4: ln1 + tcast Wf->WfT; ALL blocks fill C4 share ----------------
__global__ __launch_bounds__(256) void k4_ln1_tcast(const float* __restrict__ q,
        const float* __restrict__ oc, const float* __restrict__ g1,
        const float* __restrict__ b1, __bf16* __restrict__ Xb,
        const float* __restrict__ Wf, __bf16* __restrict__ WfT, f32x4* __restrict__ smf){
    __shared__ float sh[32 * 33];
    const int bid = blockIdx.x, t = threadIdx.x;
    if (bid < 8192){
        const int b = bid >> 11;
        const size_t base = (size_t)bid * 512;
        float2 qv = *(const float2*)(q + base + 2 * t);
        float2 ov = *(const float2*)(oc + (size_t)b * 512 + 2 * t);
        float v0 = qv.x + ov.x, v1 = qv.y + ov.y;
        float s = v0 + v1, ss = v0 * v0 + v1 * v1;
        for (int off = 32; off; off >>= 1){ s += __shfl_down(s, off); ss += __shfl_down(ss, off); }
        int wv = t >> 6, ln = t & 63;
        if (ln == 0){ sh[wv] = s; sh[4 + wv] = ss; }
        __syncthreads();
        if (t == 0){
            float S  = sh[0] + sh[1] + sh[2] + sh[3];
            float SS = sh[4] + sh[5] + sh[6] + sh[7];
            float m = S * (1.0f / 512.0f);
            float var = SS * (1.0f / 512.0f) - m * m;
            sh[0] = m; sh[1] = rsqrtf(var + 1e-5f);
        }
        __syncthreads();
        float m = sh[0], r = sh[1];
        float2 gv = *(const float2*)(g1 + 2 * t);
        float2 bv = *(const float2*)(b1 + 2 * t);
        union { __bf16 h[2]; unsigned u; } pk;
        pk.h[0] = (__bf16)((v0 - m) * r * gv.x + bv.x);
        pk.h[1] = (__bf16)((v1 - m) * r * gv.y + bv.y);
        *(unsigned*)(Xb + base + 2 * t) = pk.u;
    } else if (bid < 8448){
        int tt = bid - 8192;                   // 256 tiles over Wf [512][512]
        int c0 = (tt & 15) * 32, r0 = (tt >> 4) * 32;
        int tx = t & 31, ty = t >> 5;
        for (int i = ty; i < 32; i += 8)
            sh[i * 33 + tx] = Wf[(size_t)(r0 + i) * 512 + c0 + tx];
        __syncthreads();
        for (int i = ty; i < 32; i += 8)
            WfT[(size_t)(c0 + i) * 512 + r0 + tx] = (__bf16)sh[tx * 33 + i];
    }
    fill_slice(smf, S4, C4, bid, 8960);
}

// ---------------- k5: main GEMM (out2 = X @ Wfold, bf16 out); ALL blocks fill C5 share ----------------
__global__ __launch_bounds__(256) void k5_gemm(const __bf16* __restrict__ X,
        const __bf16* __restrict__ WfT, __bf16* __restrict__ out2, f32x4* __restrict__ smf){
    const int bid = blockIdx.x;
    if (bid < 1024){                           // 128 x 8 tiles
        gemm_tile<2>(X, WfT, out2, 512, 512, (bid >> 3) * 64, (bid & 7) * 64, 0, 512);
    }
    fill_slice(smf, S5, C5, bid, 2048);
}

// ---------------- k6: ln2; ALL blocks fill C6 share ----------------
__global__ __launch_bounds__(256) void k6_ln2(const __bf16* __restrict__ X,
        const __bf16* __restrict__ o2, const float* __restrict__ bfrow,
        const float* __restrict__ b2b, const float* __restrict__ g2,
        const float* __restrict__ b2, const float* __restrict__ keyval,
        float* __restrict__ out3, f32x4* __restrict__ smf){
    __shared__ float sh[8];
    const int bid = blockIdx.x, t = threadIdx.x;
    if (bid < 8192){
        const int b = bid >> 11;
        const size_t base = (size_t)bid * 512;
        union { unsigned u; __bf16 h[2]; } xv, yv;
        xv.u = *(const unsigned*)(X + base + 2 * t);
        yv.u = *(const unsigned*)(o2 + base + 2 * t);
        float f0 = bfrow[2 * t] + b2b[2 * t], f1 = bfrow[2 * t + 1] + b2b[2 * t + 1];
        float v0 = (float)xv.h[0] + (float)yv.h[0] + f0;
        float v1 = (float)xv.h[1] + (float)yv.h[1] + f1;
        float s = v0 + v1, ss = v0 * v0 + v1 * v1;
        for (int off = 32; off; off >>= 1){ s += __shfl_down(s, off); ss += __shfl_down(ss, off); }
        int wv = t >> 6, ln = t & 63;
        if (ln == 0){ sh[wv] = s; sh[4 + wv] = ss; }
        __syncthreads();
        if (t == 0){
            float S  = sh[0] + sh[1] + sh[2] + sh[3];
            float SS = sh[4] + sh[5] + sh[6] + sh[7];
            float m = S * (1.0f / 512.0f);
            float var = SS * (1.0f / 512.0f) - m * m;
            sh[0] = m; sh[1] = rsqrtf(var + 1e-5f);
        }
        __syncthreads();
        float m = sh[0], r = sh[1];
        float2 gv = *(const float2*)(g2 + 2 * t);
        float2 bv = *(const float2*)(b2 + 2 * t);
        float2 kv = *(const float2*)(keyval + (size_t)b * 512 + 2 * t);
        float y0 = (v0 - m) * r * gv.x + bv.x + kv.x;
        float y1 = (v1 - m) * r * gv.y + bv.y + kv.y;
        *(float2*)(out3 + base + 2 * t) = make_float2(y0, y1);
    }
    fill_slice(smf, S6, C6, bid, 8704);
}

// ---------------- launch ----------------
extern "C" void kernel_launch(void* const* d_in, const int* in_sizes, int n_in,
                              void* d_out, int out_size, void* d_ws, size_t ws_size,
                              hipStream_t stream){
    const float* query  = (const float*)d_in[0];
    const float* keyval = (const float*)d_in[1];
    // d_in[2] Wq, d_in[3] bq: provably unused (softmax is uniform regardless of Q)
    const float* Wkv = (const float*)d_in[4];
    const float* bkv = (const float*)d_in[5];
    const float* Wff = (const float*)d_in[6];
    const float* bff = (const float*)d_in[7];
    const float* g1  = (const float*)d_in[8];
    const float* b1  = (const float*)d_in[9];
    const float* W2a = (const float*)d_in[10];
    const float* b2a = (const float*)d_in[11];
    const float* W2b = (const float*)d_in[12];
    const float* b2b = (const float*)d_in[13];
    const float* g2  = (const float*)d_in[14];
    const float* b2  = (const float*)d_in[15];

    float* out3 = (float*)d_out;
    f32x4* smf  = (f32x4*)(out3 + OUT3_N);

    // scratch (~24 MB): prefer d_ws; fall back to the sm region (filled last)
    char* base = (ws_size >= (64ull << 20)) ? (char*)d_ws : (char*)smf;
    float*  t_Wf   = (float*)base;                      // [576][512] fp32 (row 512 = b2a@W2b)
    float*  t_V    = t_Wf + 294912;                     // [4][1200]
    float*  t_oc   = t_V + 4800;                        // [4][512]
    __bf16* t_A1   = (__bf16*)(t_oc + 2048);            // [576][2048]
    __bf16* t_W2bT = t_A1 + 1179648;                    // [512][2048]
    __bf16* t_WfT  = t_W2bT + 1048576;                  // [512][512]
    __bf16* t_X    = t_WfT + 262144;                    // [8192][512]
    __bf16* t_out2 = t_X + 4194304;                     // [8192][512] bf16

    // zero split-K accumulators (Wf, V, oc contiguous = 301,760 floats)
    (void)hipMemsetAsync(t_Wf, 0, 301760 * sizeof(float), stream);
    k1_prep_kv<<<2848, 256, 0, stream>>>(W2a, b2a, t_A1, W2b, t_W2bT,
                                         keyval, Wkv, bkv, t_V, smf);
    k3_fold_oc<<<2048, 256, 0, stream>>>(t_A1, t_W2bT, t_Wf, t_V, Wff, bff, t_oc, smf);
    k4_ln1_tcast<<<8960, 256, 0, stream>>>(query, t_oc, g1, b1, t_X, t_Wf, t_WfT, smf);
    k5_gemm<<<2048, 256, 0, stream>>>(t_X, t_WfT, t_out2, smf);
    // bfold row = row 512 of Wf (starts at 512*512)
    k6_ln2<<<8704, 256, 0, stream>>>(t_X, t_out2, t_Wf + 262144, b2b, g2, b2,
                                     keyval, out3, smf);
}